// Round 11
// baseline (697.181 us; speedup 1.0000x reference)
//
#include <hip/hip_runtime.h>

#define N_ROWS 16384
#define DIM 256
#define MARGINF 0.3f
#define CH 2048
#define TILES 32
#define LOG2E 1.44269504089f

typedef float f32x4 __attribute__((ext_vector_type(4)));
typedef long lng;

__device__ __forceinline__ float fexp2(float x) {
#if __has_builtin(__builtin_amdgcn_exp2f)
  return __builtin_amdgcn_exp2f(x);
#else
  return exp2f(x);
#endif
}

// ------------------------------------------------------------------
// float -> OCP e4m3fn (manual fallback)
// ------------------------------------------------------------------
__device__ __forceinline__ unsigned char to_e4m3(float f) {
  unsigned u = __float_as_uint(f);
  unsigned sign = (u >> 24) & 0x80u;
  float a = fabsf(f);
  if (a >= 448.0f) return (unsigned char)(sign | 0x7eu);
  if (a < 0.015625f) {
    int q = (int)(a * 512.0f + 0.5f);
    return (unsigned char)(sign | (unsigned)q);
  }
  int e;
  float m = frexpf(a, &e);
  float mant = 2.0f * m;
  int e8 = e - 1;
  int mb = (int)(mant * 8.0f + 0.5f) - 8;
  if (mb == 8) { mb = 0; ++e8; if (e8 > 8) return (unsigned char)(sign | 0x7eu); }
  return (unsigned char)(sign | (unsigned)((e8 + 7) << 3) | (unsigned)mb);
}

__device__ __forceinline__ unsigned int pack4_e4m3(float a, float b, float c, float d) {
#if __has_builtin(__builtin_amdgcn_cvt_pk_fp8_f32)
  int lo = __builtin_amdgcn_cvt_pk_fp8_f32(a, b, 0, false);
  int r = __builtin_amdgcn_cvt_pk_fp8_f32(c, d, lo, true);
  return (unsigned int)r;
#else
  return (unsigned int)to_e4m3(a) | ((unsigned int)to_e4m3(b) << 8) |
         ((unsigned int)to_e4m3(c) << 16) | ((unsigned int)to_e4m3(d) << 24);
#endif
}

// ------------------------------------------------------------------
// Kernel 1: norms + exact fp32 diag cosine + fp8 rows.
// x-side pre-scaled by log2(e) so the GEMM's exp(S) = exp2(S').
// ------------------------------------------------------------------
__global__ __launch_bounds__(256) void normalize_kernel(
    const float* __restrict__ x, const float* __restrict__ y,
    unsigned int* __restrict__ xn8, unsigned int* __restrict__ yn8,
    float* __restrict__ diagF) {
  const int wid = threadIdx.x >> 6;
  const int lane = threadIdx.x & 63;
  const int r = blockIdx.x * 4 + wid;  // 0..16383
  const float4 vx = *reinterpret_cast<const float4*>(x + (size_t)r * DIM + lane * 4);
  const float4 vy = *reinterpret_cast<const float4*>(y + (size_t)r * DIM + lane * 4);
  float sx = vx.x * vx.x + vx.y * vx.y + vx.z * vx.z + vx.w * vx.w;
  float sy = vy.x * vy.x + vy.y * vy.y + vy.z * vy.z + vy.w * vy.w;
  float sxy = vx.x * vy.x + vx.y * vy.y + vx.z * vy.z + vx.w * vy.w;
  #pragma unroll
  for (int off = 32; off; off >>= 1) {
    sx += __shfl_xor(sx, off);
    sy += __shfl_xor(sy, off);
    sxy += __shfl_xor(sxy, off);
  }
  const float scx = LOG2E / fmaxf(sqrtf(sx), 1e-8f);   // log2e folded into A
  const float scy = 1.0f / fmaxf(sqrtf(sy), 1e-8f);
  if (lane == 0) diagF[r] = sxy * (scx / LOG2E) * scy;
  xn8[(size_t)r * 64 + lane] = pack4_e4m3(vx.x * scx, vx.y * scx, vx.z * scx, vx.w * scx);
  yn8[(size_t)r * 64 + lane] = pack4_e4m3(vy.x * scy, vy.y * scy, vy.z * scy, vy.w * scy);
}

// ------------------------------------------------------------------
// Stage one 64-col x 256-K fp8 panel (16 KB) into LDS. [verbatim R10]
// ------------------------------------------------------------------
__device__ __forceinline__ void stage_panel(const unsigned char* __restrict__ src,
                                            int colBase, unsigned char* ldsBase, int tid) {
  const int wid = tid >> 6;
  #pragma unroll
  for (int it = 0; it < 4; ++it) {
    const int id = it * 256 + tid;      // 1024 x 16B granules
    const int col = id >> 4;            // 0..63
    const int slot = id & 15;
    const int srcg = slot ^ (col & 7);
    const unsigned char* gp = src + (size_t)(colBase + col) * DIM + srcg * 16;
    unsigned char* l = ldsBase + (size_t)(it * 256 + wid * 64) * 16;  // wave-uniform
    __builtin_amdgcn_global_load_lds(
        (const __attribute__((address_space(1))) unsigned int*)gp,
        (__attribute__((address_space(3))) unsigned int*)l, 16, 0, 0);
  }
}

// ------------------------------------------------------------------
// Kernel 2: fp8 GEMM + exp2. R10's datapath, software-pipelined
// epilogue: two static acc sets (accA/accB); FINISH(t-1) is emitted
// inside tile t's MFMA stream so in-order issue fills MFMA pipe-stall
// slots with the previous tile's exp2/add VALU. LDS exactly 32 KB.
// ------------------------------------------------------------------
__global__ __launch_bounds__(256, 3) void gemm_exp_kernel(
    const unsigned char* __restrict__ xn8, const unsigned char* __restrict__ yn8,
    float* __restrict__ diag8, float* __restrict__ rowpart,
    float* __restrict__ colpartW, float* __restrict__ rowsumG,
    float* __restrict__ colsumG, int use_scratch) {
  __shared__ unsigned char ldsB[2][16384];  // exactly 32 KB

  const int tid = threadIdx.x;
  const int lane = tid & 63;
  const int wid = tid >> 6;
  const int wm = wid >> 1, wn = wid & 1;
  const int grp = lane >> 4, li = lane & 15;

  const int bid = blockIdx.x;
  const int chunk = bid & 7;        // XCD round-robin
  const int band = bid >> 3;        // 0..127
  const int rowBase = band * 128;
  const int colBase = chunk * CH;

  // ---- A band -> registers (fp8: 8B per ks-frag) [verbatim R10] ----
  lng a[4][8];
  #pragma unroll
  for (int m = 0; m < 4; ++m)
    #pragma unroll
    for (int ks = 0; ks < 8; ++ks) {
      const int row = rowBase + wm * 64 + m * 16 + li;
      a[m][ks] = *reinterpret_cast<const lng*>(
          xn8 + (size_t)row * DIM + ks * 32 + grp * 8);
    }

  stage_panel(yn8, colBase, &ldsB[0][0], tid);
  __syncthreads();

  float rsum[4][4];
  #pragma unroll
  for (int m = 0; m < 4; ++m)
    #pragma unroll
    for (int j = 0; j < 4; ++j) rsum[m][j] = 0.0f;

  const int bandDelta = band - chunk * 16;  // diag stripe iff in [0,16)
  const int col0 = wn * 32 + li;
  const int boff = (grp & 1) * 8;

  f32x4 accA[4][2], accB[4][2];

  // COMPUTE tile t into acc (ds_reads + 64 MFMA), statically inlined.
  auto COMPUTE = [&](int t, f32x4 (&acc)[4][2]) __attribute__((always_inline)) {
    const unsigned char* Bp = &ldsB[t & 1][0];
    #pragma unroll
    for (int m = 0; m < 4; ++m) { acc[m][0] = (f32x4)(0.0f); acc[m][1] = (f32x4)(0.0f); }
    #pragma unroll
    for (int ks = 0; ks < 8; ++ks) {
      const int g = 2 * ks + (grp >> 1);
      const lng b0 = *reinterpret_cast<const lng*>(
          Bp + (size_t)col0 * 256 + ((g ^ (li & 7)) * 16) + boff);
      const lng b1 = *reinterpret_cast<const lng*>(
          Bp + (size_t)(col0 + 16) * 256 + ((g ^ (li & 7)) * 16) + boff);
      #pragma unroll
      for (int m = 0; m < 4; ++m) {
        acc[m][0] = __builtin_amdgcn_mfma_f32_16x16x32_fp8_fp8(a[m][ks], b0, acc[m][0], 0, 0, 0);
        acc[m][1] = __builtin_amdgcn_mfma_f32_16x16x32_fp8_fp8(a[m][ks], b1, acc[m][1], 0, 0, 0);
      }
    }
  };

  // FINISH tile tf from acc: exp2 + partials + diag capture [R10 epilogue]
  auto FINISH = [&](int tf, f32x4 (&acc)[4][2]) __attribute__((always_inline)) {
    float cs0 = 0.0f, cs1 = 0.0f;
    const bool maybeDiag = (bandDelta == (tf >> 1));
    #pragma unroll
    for (int m = 0; m < 4; ++m) {
      #pragma unroll
      for (int j = 0; j < 4; ++j) {
        const float s0 = acc[m][0][j];
        const float s1 = acc[m][1][j];
        const float e0 = fexp2(s0);
        const float e1 = fexp2(s1);
        rsum[m][j] += e0 + e1;
        cs0 += e0;
        cs1 += e1;
        if (maybeDiag) {
          const int rg = rowBase + wm * 64 + m * 16 + grp * 4 + j;
          const int cg = colBase + tf * 64 + wn * 32 + li;
          if (rg == cg) diag8[rg] = s0;
          if (rg == cg + 16) diag8[rg] = s1;
        }
      }
    }
    cs0 += __shfl_xor(cs0, 16); cs0 += __shfl_xor(cs0, 32);
    cs1 += __shfl_xor(cs1, 16); cs1 += __shfl_xor(cs1, 32);
    if (grp == 0) {
      const int c = tf * 64 + wn * 32 + li;
      if (use_scratch) {
        colpartW[((size_t)(wm * 128 + band)) * N_ROWS + colBase + c] = cs0;
        colpartW[((size_t)(wm * 128 + band)) * N_ROWS + colBase + c + 16] = cs1;
      } else {
        atomicAdd(&colsumG[colBase + c], cs0);
        atomicAdd(&colsumG[colBase + c + 16], cs1);
      }
    }
  };

  // ---- pipelined loop: COMPUTE(t) || FINISH(t-1), acc ping-pong ----
  stage_panel(yn8, colBase + 64, &ldsB[1][0], tid);   // stage tile 1
  COMPUTE(0, accA);
  __syncthreads();

  for (int tt = 1; tt < TILES; tt += 2) {
    if (tt + 1 < TILES)
      stage_panel(yn8, colBase + (tt + 1) * 64, &ldsB[(tt + 1) & 1][0], tid);
    COMPUTE(tt, accB);
    FINISH(tt - 1, accA);
    __syncthreads();
    if (tt + 1 < TILES) {
      if (tt + 2 < TILES)
        stage_panel(yn8, colBase + (tt + 2) * 64, &ldsB[(tt + 2) & 1][0], tid);
      COMPUTE(tt + 1, accA);
      FINISH(tt, accB);
      __syncthreads();
    }
  }
  FINISH(TILES - 1, accB);   // TILES even: last tile landed in accB

  // ---- cross-wave row-sum reduction (reuse ldsB) [verbatim R10] ----
  __syncthreads();
  float* rowTmp = reinterpret_cast<float*>(&ldsB[0][0]);  // [2 wn][128]
  #pragma unroll
  for (int m = 0; m < 4; ++m) {
    #pragma unroll
    for (int j = 0; j < 4; ++j) {
      float v = rsum[m][j];
      v += __shfl_xor(v, 1); v += __shfl_xor(v, 2);
      v += __shfl_xor(v, 4); v += __shfl_xor(v, 8);
      if (li == 0) rowTmp[wn * 128 + wm * 64 + m * 16 + grp * 4 + j] = v;
    }
  }
  __syncthreads();
  if (tid < 128) {
    const float v = rowTmp[tid] + rowTmp[128 + tid];
    if (use_scratch) rowpart[(size_t)chunk * N_ROWS + rowBase + tid] = v;
    else atomicAdd(&rowsumG[rowBase + tid], v);
  }
}

// ------------------------------------------------------------------
// Kernel 3: reduce partials + final loss. [verbatim R10]
// ------------------------------------------------------------------
__global__ __launch_bounds__(256) void finalize_kernel(
    const float* __restrict__ rowpart, const float* __restrict__ colpartW,
    const float* __restrict__ rowsumG, const float* __restrict__ colsumG,
    const float* __restrict__ diag8, const float* __restrict__ diagF,
    float* __restrict__ out, int use_scratch) {
  __shared__ float red[4];
  const int i = blockIdx.x * 256 + threadIdx.x;
  float rs, cs;
  if (use_scratch) {
    rs = 0.0f;
    #pragma unroll
    for (int c = 0; c < 8; ++c) rs += rowpart[(size_t)c * N_ROWS + i];
    cs = 0.0f;
    #pragma unroll 8
    for (int b = 0; b < 256; ++b) cs += colpartW[(size_t)b * N_ROWS + i];
  } else {
    rs = rowsumG[i];
    cs = colsumG[i];
  }
  const float e8 = fexp2(diag8[i]);           // matches gemm's exp2 exactly
  const float mm = __expf(diagF[i] - MARGINF);
  float v = mm / (mm + rs - e8) + mm / (mm + cs - e8);
  #pragma unroll
  for (int off = 32; off; off >>= 1) v += __shfl_xor(v, off);
  if ((threadIdx.x & 63) == 0) red[threadIdx.x >> 6] = v;
  __syncthreads();
  if (threadIdx.x == 0) {
    const float t = red[0] + red[1] + red[2] + red[3];
    atomicAdd(out, -t / (float)N_ROWS);
  }
}

// ------------------------------------------------------------------
extern "C" void kernel_launch(void* const* d_in, const int* in_sizes, int n_in,
                              void* d_out, int out_size, void* d_ws, size_t ws_size,
                              hipStream_t stream) {
  const float* x = (const float*)d_in[0];
  const float* y = (const float*)d_in[1];
  char* ws = (char*)d_ws;
  unsigned char* xn8 = (unsigned char*)ws;                   // 4 MiB
  unsigned char* yn8 = (unsigned char*)(ws + (4u << 20));    // 4 MiB
  float* diag8    = (float*)(ws + (8u << 20));               // 64 KiB
  float* diagF    = (float*)(ws + (8u << 20) + 65536);       // 64 KiB
  float* rowpart  = (float*)(ws + (8u << 20) + 131072);      // 512 KiB [8][N]
  float* colpartW = (float*)(ws + (8u << 20) + 131072 + 524288);  // 16 MiB [256][N]
  float* rowsumG = rowpart;                                  // fallback aliases
  float* colsumG = rowpart + N_ROWS;
  const size_t need_scratch = (8u << 20) + 131072 + 524288 + (16u << 20);
  const int use_scratch = (ws_size >= need_scratch) ? 1 : 0;

  hipMemsetAsync(d_out, 0, sizeof(float), stream);
  if (!use_scratch) hipMemsetAsync(rowsumG, 0, 2 * N_ROWS * sizeof(float), stream);
  normalize_kernel<<<4096, 256, 0, stream>>>(x, y, (unsigned int*)xn8,
                                             (unsigned int*)yn8, diagF);
  gemm_exp_kernel<<<1024, 256, 0, stream>>>(xn8, yn8, diag8, rowpart, colpartW,
                                            rowsumG, colsumG, use_scratch);
  finalize_kernel<<<64, 256, 0, stream>>>(rowpart, colpartW, rowsumG, colsumG,
                                          diag8, diagF, (float*)d_out, use_scratch);
}

// Round 12
// 137.366 us; speedup vs baseline: 5.0754x; 5.0754x over previous
//
#include <hip/hip_runtime.h>

#define N_ROWS 16384
#define DIM 256
#define MARGINF 0.3f
#define CH 2048
#define NT 64            // 32-col tiles per chunk
#define LOG2E 1.44269504089f

typedef float f32x4 __attribute__((ext_vector_type(4)));
typedef long lng;

__device__ __forceinline__ float fexp2(float x) {
#if __has_builtin(__builtin_amdgcn_exp2f)
  return __builtin_amdgcn_exp2f(x);
#else
  return exp2f(x);
#endif
}

// ------------------------------------------------------------------
// float -> OCP e4m3fn (manual fallback)
// ------------------------------------------------------------------
__device__ __forceinline__ unsigned char to_e4m3(float f) {
  unsigned u = __float_as_uint(f);
  unsigned sign = (u >> 24) & 0x80u;
  float a = fabsf(f);
  if (a >= 448.0f) return (unsigned char)(sign | 0x7eu);
  if (a < 0.015625f) {
    int q = (int)(a * 512.0f + 0.5f);
    return (unsigned char)(sign | (unsigned)q);
  }
  int e;
  float m = frexpf(a, &e);
  float mant = 2.0f * m;
  int e8 = e - 1;
  int mb = (int)(mant * 8.0f + 0.5f) - 8;
  if (mb == 8) { mb = 0; ++e8; if (e8 > 8) return (unsigned char)(sign | 0x7eu); }
  return (unsigned char)(sign | (unsigned)((e8 + 7) << 3) | (unsigned)mb);
}

__device__ __forceinline__ unsigned int pack4_e4m3(float a, float b, float c, float d) {
#if __has_builtin(__builtin_amdgcn_cvt_pk_fp8_f32)
  int lo = __builtin_amdgcn_cvt_pk_fp8_f32(a, b, 0, false);
  int r = __builtin_amdgcn_cvt_pk_fp8_f32(c, d, lo, true);
  return (unsigned int)r;
#else
  return (unsigned int)to_e4m3(a) | ((unsigned int)to_e4m3(b) << 8) |
         ((unsigned int)to_e4m3(c) << 16) | ((unsigned int)to_e4m3(d) << 24);
#endif
}

// ------------------------------------------------------------------
// Kernel 1: norms + exact fp32 diag cosine + fp8 rows.
// x-side pre-scaled by log2(e) so the GEMM's exp(S) = exp2(S').
// ------------------------------------------------------------------
__global__ __launch_bounds__(256) void normalize_kernel(
    const float* __restrict__ x, const float* __restrict__ y,
    unsigned int* __restrict__ xn8, unsigned int* __restrict__ yn8,
    float* __restrict__ diagF) {
  const int wid = threadIdx.x >> 6;
  const int lane = threadIdx.x & 63;
  const int r = blockIdx.x * 4 + wid;  // 0..16383
  const float4 vx = *reinterpret_cast<const float4*>(x + (size_t)r * DIM + lane * 4);
  const float4 vy = *reinterpret_cast<const float4*>(y + (size_t)r * DIM + lane * 4);
  float sx = vx.x * vx.x + vx.y * vx.y + vx.z * vx.z + vx.w * vx.w;
  float sy = vy.x * vy.x + vy.y * vy.y + vy.z * vy.z + vy.w * vy.w;
  float sxy = vx.x * vy.x + vx.y * vy.y + vx.z * vy.z + vx.w * vy.w;
  #pragma unroll
  for (int off = 32; off; off >>= 1) {
    sx += __shfl_xor(sx, off);
    sy += __shfl_xor(sy, off);
    sxy += __shfl_xor(sxy, off);
  }
  const float scx = LOG2E / fmaxf(sqrtf(sx), 1e-8f);   // log2e folded into A
  const float scy = 1.0f / fmaxf(sqrtf(sy), 1e-8f);
  if (lane == 0) diagF[r] = sxy * (scx / LOG2E) * scy;
  xn8[(size_t)r * 64 + lane] = pack4_e4m3(vx.x * scx, vx.y * scx, vx.z * scx, vx.w * scx);
  yn8[(size_t)r * 64 + lane] = pack4_e4m3(vy.x * scy, vy.y * scy, vy.z * scy, vy.w * scy);
}

// ------------------------------------------------------------------
// Per-WAVE stage: 32 cols x 256 K fp8 (8 KB) into this wave's slab.
// 8 global_load_lds per wave; granule XOR-swizzle (col&7) on the
// GLOBAL side, linear LDS dest (same verified scheme as R10).
// ------------------------------------------------------------------
__device__ __forceinline__ void stage_wave(const unsigned char* __restrict__ src,
                                           int colBase32, unsigned char* slab, int lane) {
  #pragma unroll
  for (int it = 0; it < 8; ++it) {
    const int id = it * 64 + lane;      // 512 x 16B granules
    const int col = id >> 4;            // 0..31
    const int slot = id & 15;
    const unsigned char* gp =
        src + (unsigned)((colBase32 + col) * DIM + ((slot ^ (col & 7)) << 4));
    unsigned char* l = slab + it * 1024;  // wave-uniform base (+lane*16 by HW)
    __builtin_amdgcn_global_load_lds(
        (const __attribute__((address_space(1))) unsigned int*)gp,
        (__attribute__((address_space(3))) unsigned int*)l, 16, 0, 0);
  }
}

// ------------------------------------------------------------------
// Kernel 2: barrier-free fp8 GEMM + exp2.
// Each wave: 64-row band x 2048-col chunk, private 2x8KB LDS slab,
// counted per-wave vmcnt (stage(t)=oldest 8; +2 stores; +8 in flight
// -> vmcnt(8/10/2)), NO __syncthreads. Datapath verbatim from R10.
// Pipe contention self-organizes the 2 SIMD-waves into anti-phase.
// ------------------------------------------------------------------
__global__ __launch_bounds__(256, 2) void gemm_exp_kernel(
    const unsigned char* __restrict__ xn8, const unsigned char* __restrict__ yn8,
    float* __restrict__ rowpart, float* __restrict__ colpartW,
    float* __restrict__ rowsumG, float* __restrict__ colsumG, int use_scratch) {
  __shared__ unsigned char lds[4][2][8192];   // 64 KB: per-wave double buffer

  const int tid = threadIdx.x;
  const int lane = tid & 63;
  const int wid = tid >> 6;
  const int grp = lane >> 4, li = lane & 15;

  const int bid = blockIdx.x;
  const int chunk = bid & 7;               // XCD round-robin; 512KB B/XCD in L2
  const int band = (bid >> 3) * 4 + wid;   // 0..255 (64-row band per wave)
  const int rowBase = band * 64;
  const int colBase = chunk * CH;

  // ---- A: 64 rows x 256 K fp8 -> a[4][8] (64 VGPR) [R10 pattern] ----
  lng a[4][8];
  #pragma unroll
  for (int m = 0; m < 4; ++m)
    #pragma unroll
    for (int ks = 0; ks < 8; ++ks) {
      const int row = rowBase + m * 16 + li;
      a[m][ks] = *reinterpret_cast<const lng*>(
          xn8 + (size_t)row * DIM + ks * 32 + grp * 8);
    }

  float rsum[4][4];
  #pragma unroll
  for (int m = 0; m < 4; ++m)
    #pragma unroll
    for (int j = 0; j < 4; ++j) rsum[m][j] = 0.0f;

  unsigned char* slab0 = &lds[wid][0][0];
  unsigned char* slab1 = &lds[wid][1][0];
  const int boff = (grp & 1) * 8;

  stage_wave(yn8, colBase, slab0, lane);
  __builtin_amdgcn_sched_barrier(0);

  for (int t = 0; t < NT; ++t) {
    // issue stage(t+1) first (max latency hiding), then wait for stage(t):
    // outstanding (issue order): [stage(t) 8][stores(t-1) 2][stage(t+1) 8]
    if (t + 1 < NT)
      stage_wave(yn8, colBase + (t + 1) * 32, (t & 1) ? slab0 : slab1, lane);
    __builtin_amdgcn_sched_barrier(0);
    if (t == 0)          asm volatile("s_waitcnt vmcnt(8)" ::: "memory");
    else if (t + 1 < NT) asm volatile("s_waitcnt vmcnt(10)" ::: "memory");
    else                 asm volatile("s_waitcnt vmcnt(2)" ::: "memory");
    __builtin_amdgcn_sched_barrier(0);

    const unsigned char* Bp = (t & 1) ? slab1 : slab0;
    f32x4 acc[4][2];
    #pragma unroll
    for (int m = 0; m < 4; ++m) { acc[m][0] = (f32x4)(0.0f); acc[m][1] = (f32x4)(0.0f); }

    __builtin_amdgcn_s_setprio(1);
    #pragma unroll
    for (int ks = 0; ks < 8; ++ks) {
      const int g = 2 * ks + (grp >> 1);
      const lng b0 = *reinterpret_cast<const lng*>(
          Bp + (size_t)li * 256 + ((g ^ (li & 7)) * 16) + boff);
      const lng b1 = *reinterpret_cast<const lng*>(
          Bp + (size_t)(li + 16) * 256 + ((g ^ (li & 7)) * 16) + boff);
      #pragma unroll
      for (int m = 0; m < 4; ++m) {
        acc[m][0] = __builtin_amdgcn_mfma_f32_16x16x32_fp8_fp8(a[m][ks], b0, acc[m][0], 0, 0, 0);
        acc[m][1] = __builtin_amdgcn_mfma_f32_16x16x32_fp8_fp8(a[m][ks], b1, acc[m][1], 0, 0, 0);
      }
    }
    __builtin_amdgcn_s_setprio(0);

    // ---- epilogue: exp2 + row/col partials (no diag machinery) ----
    float cs0 = 0.0f, cs1 = 0.0f;
    #pragma unroll
    for (int m = 0; m < 4; ++m) {
      #pragma unroll
      for (int j = 0; j < 4; ++j) {
        const float e0 = fexp2(acc[m][0][j]);
        const float e1 = fexp2(acc[m][1][j]);
        rsum[m][j] += e0 + e1;
        cs0 += e0;
        cs1 += e1;
      }
    }
    cs0 += __shfl_xor(cs0, 16); cs0 += __shfl_xor(cs0, 32);
    cs1 += __shfl_xor(cs1, 16); cs1 += __shfl_xor(cs1, 32);
    if (grp == 0) {  // exactly 2 vmem ops per wave per tile (vmcnt audit)
      const int c = colBase + t * 32 + li;
      if (use_scratch) {
        colpartW[(size_t)band * N_ROWS + c] = cs0;
        colpartW[(size_t)band * N_ROWS + c + 16] = cs1;
      } else {
        atomicAdd(&colsumG[c], cs0);
        atomicAdd(&colsumG[c + 16], cs1);
      }
    }
  }

  // ---- row sums: wave-exclusive rows, direct write ----
  #pragma unroll
  for (int m = 0; m < 4; ++m) {
    #pragma unroll
    for (int j = 0; j < 4; ++j) {
      float v = rsum[m][j];
      v += __shfl_xor(v, 1); v += __shfl_xor(v, 2);
      v += __shfl_xor(v, 4); v += __shfl_xor(v, 8);
      if (li == 0) {
        const int r = rowBase + m * 16 + grp * 4 + j;
        if (use_scratch) rowpart[(size_t)chunk * N_ROWS + r] = v;
        else atomicAdd(&rowsumG[r], v);
      }
    }
  }
}

// ------------------------------------------------------------------
// Kernel 3: reduce partials + final loss. e8 uses the fp32 diagonal
// (error vs the fp8 in-matrix diagonal ~1e-10 on the output; budget
// 1.8e-6 -> negligible).
// ------------------------------------------------------------------
__global__ __launch_bounds__(256) void finalize_kernel(
    const float* __restrict__ rowpart, const float* __restrict__ colpartW,
    const float* __restrict__ rowsumG, const float* __restrict__ colsumG,
    const float* __restrict__ diagF, float* __restrict__ out, int use_scratch) {
  __shared__ float red[4];
  const int i = blockIdx.x * 256 + threadIdx.x;
  float rs, cs;
  if (use_scratch) {
    rs = 0.0f;
    #pragma unroll
    for (int c = 0; c < 8; ++c) rs += rowpart[(size_t)c * N_ROWS + i];
    cs = 0.0f;
    #pragma unroll 8
    for (int b = 0; b < 256; ++b) cs += colpartW[(size_t)b * N_ROWS + i];
  } else {
    rs = rowsumG[i];
    cs = colsumG[i];
  }
  const float d = diagF[i];
  const float e8 = fexp2(LOG2E * d);          // ~= gemm's exp2(S'_ii)
  const float mm = __expf(d - MARGINF);
  float v = mm / (mm + rs - e8) + mm / (mm + cs - e8);
  #pragma unroll
  for (int off = 32; off; off >>= 1) v += __shfl_xor(v, off);
  if ((threadIdx.x & 63) == 0) red[threadIdx.x >> 6] = v;
  __syncthreads();
  if (threadIdx.x == 0) {
    const float t = red[0] + red[1] + red[2] + red[3];
    atomicAdd(out, -t / (float)N_ROWS);
  }
}

// ------------------------------------------------------------------
extern "C" void kernel_launch(void* const* d_in, const int* in_sizes, int n_in,
                              void* d_out, int out_size, void* d_ws, size_t ws_size,
                              hipStream_t stream) {
  const float* x = (const float*)d_in[0];
  const float* y = (const float*)d_in[1];
  char* ws = (char*)d_ws;
  unsigned char* xn8 = (unsigned char*)ws;                   // 4 MiB
  unsigned char* yn8 = (unsigned char*)(ws + (4u << 20));    // 4 MiB
  float* diagF    = (float*)(ws + (8u << 20));               // 64 KiB
  float* rowpart  = (float*)(ws + (8u << 20) + 65536);       // 512 KiB [8][N]
  float* colpartW = (float*)(ws + (8u << 20) + 65536 + 524288);  // 16 MiB [256][N]
  float* rowsumG = rowpart;                                  // fallback aliases
  float* colsumG = rowpart + N_ROWS;
  const size_t need_scratch = (8u << 20) + 65536 + 524288 + (16u << 20);
  const int use_scratch = (ws_size >= need_scratch) ? 1 : 0;

  hipMemsetAsync(d_out, 0, sizeof(float), stream);
  if (!use_scratch) hipMemsetAsync(rowsumG, 0, 2 * N_ROWS * sizeof(float), stream);
  normalize_kernel<<<4096, 256, 0, stream>>>(x, y, (unsigned int*)xn8,
                                             (unsigned int*)yn8, diagF);
  gemm_exp_kernel<<<512, 256, 0, stream>>>(xn8, yn8, rowpart, colpartW,
                                           rowsumG, colsumG, use_scratch);
  finalize_kernel<<<64, 256, 0, stream>>>(rowpart, colpartW, rowsumG, colsumG,
                                          diagF, (float*)d_out, use_scratch);
}

// Round 13
// 126.816 us; speedup vs baseline: 5.4976x; 1.0832x over previous
//
#include <hip/hip_runtime.h>

#define N_ROWS 16384
#define DIM 256
#define MARGINF 0.3f
#define CH 2048
#define NT 64            // 32-col tiles per chunk
#define LOG2E 1.44269504089f

typedef float f32x4 __attribute__((ext_vector_type(4)));
typedef int i32x4 __attribute__((ext_vector_type(4)));
typedef int i32x8 __attribute__((ext_vector_type(8)));
typedef long lng;

__device__ __forceinline__ float fexp2(float x) {
#if __has_builtin(__builtin_amdgcn_exp2f)
  return __builtin_amdgcn_exp2f(x);
#else
  return exp2f(x);
#endif
}

// ------------------------------------------------------------------
// float -> OCP e4m3fn (manual fallback)
// ------------------------------------------------------------------
__device__ __forceinline__ unsigned char to_e4m3(float f) {
  unsigned u = __float_as_uint(f);
  unsigned sign = (u >> 24) & 0x80u;
  float a = fabsf(f);
  if (a >= 448.0f) return (unsigned char)(sign | 0x7eu);
  if (a < 0.015625f) {
    int q = (int)(a * 512.0f + 0.5f);
    return (unsigned char)(sign | (unsigned)q);
  }
  int e;
  float m = frexpf(a, &e);
  float mant = 2.0f * m;
  int e8 = e - 1;
  int mb = (int)(mant * 8.0f + 0.5f) - 8;
  if (mb == 8) { mb = 0; ++e8; if (e8 > 8) return (unsigned char)(sign | 0x7eu); }
  return (unsigned char)(sign | (unsigned)((e8 + 7) << 3) | (unsigned)mb);
}

__device__ __forceinline__ unsigned int pack4_e4m3(float a, float b, float c, float d) {
#if __has_builtin(__builtin_amdgcn_cvt_pk_fp8_f32)
  int lo = __builtin_amdgcn_cvt_pk_fp8_f32(a, b, 0, false);
  int r = __builtin_amdgcn_cvt_pk_fp8_f32(c, d, lo, true);
  return (unsigned int)r;
#else
  return (unsigned int)to_e4m3(a) | ((unsigned int)to_e4m3(b) << 8) |
         ((unsigned int)to_e4m3(c) << 16) | ((unsigned int)to_e4m3(d) << 24);
#endif
}

// ------------------------------------------------------------------
// Kernel 1: norms + exact fp32 diag cosine + fp8 rows.
// x-side pre-scaled by log2(e) so the GEMM's exp(S) = exp2(S').
// ------------------------------------------------------------------
__global__ __launch_bounds__(256) void normalize_kernel(
    const float* __restrict__ x, const float* __restrict__ y,
    unsigned int* __restrict__ xn8, unsigned int* __restrict__ yn8,
    float* __restrict__ diagF) {
  const int wid = threadIdx.x >> 6;
  const int lane = threadIdx.x & 63;
  const int r = blockIdx.x * 4 + wid;  // 0..16383
  const float4 vx = *reinterpret_cast<const float4*>(x + (size_t)r * DIM + lane * 4);
  const float4 vy = *reinterpret_cast<const float4*>(y + (size_t)r * DIM + lane * 4);
  float sx = vx.x * vx.x + vx.y * vx.y + vx.z * vx.z + vx.w * vx.w;
  float sy = vy.x * vy.x + vy.y * vy.y + vy.z * vy.z + vy.w * vy.w;
  float sxy = vx.x * vy.x + vx.y * vy.y + vx.z * vy.z + vx.w * vy.w;
  #pragma unroll
  for (int off = 32; off; off >>= 1) {
    sx += __shfl_xor(sx, off);
    sy += __shfl_xor(sy, off);
    sxy += __shfl_xor(sxy, off);
  }
  const float scx = LOG2E / fmaxf(sqrtf(sx), 1e-8f);   // log2e folded into A
  const float scy = 1.0f / fmaxf(sqrtf(sy), 1e-8f);
  if (lane == 0) diagF[r] = sxy * (scx / LOG2E) * scy;
  xn8[(size_t)r * 64 + lane] = pack4_e4m3(vx.x * scx, vx.y * scx, vx.z * scx, vx.w * scx);
  yn8[(size_t)r * 64 + lane] = pack4_e4m3(vy.x * scy, vy.y * scy, vy.z * scy, vy.w * scy);
}

// ------------------------------------------------------------------
// Per-WAVE stage: 32 cols x 256 K fp8 (8 KB) into this wave's slab.
// [verbatim R12 - passed] Granule XOR-swizzle (col&7) on the GLOBAL
// side, linear LDS dest.
// ------------------------------------------------------------------
__device__ __forceinline__ void stage_wave(const unsigned char* __restrict__ src,
                                           int colBase32, unsigned char* slab, int lane) {
  #pragma unroll
  for (int it = 0; it < 8; ++it) {
    const int id = it * 64 + lane;      // 512 x 16B granules
    const int col = id >> 4;            // 0..31
    const int slot = id & 15;
    const unsigned char* gp =
        src + (unsigned)((colBase32 + col) * DIM + ((slot ^ (col & 7)) << 4));
    unsigned char* l = slab + it * 1024;  // wave-uniform base (+lane*16 by HW)
    __builtin_amdgcn_global_load_lds(
        (const __attribute__((address_space(1))) unsigned int*)gp,
        (__attribute__((address_space(3))) unsigned int*)l, 16, 0, 0);
  }
}

// ------------------------------------------------------------------
// Kernel 2: barrier-free MX-fp8 GEMM + exp2.
// R12's proven structure (per-wave 2x8KB slab, counted per-wave vmcnt
// 8/10/2, zero __syncthreads). MFMA upgraded to scaled
// mfma_f32_16x16x128_f8f6f4 with unit scales (E8M0 127 = 2^0): 2x the
// non-scaled fp8 rate, SAME 16x16 C/D layout -> epilogue unchanged.
// Per tile: 8 ds_read_b128 + 16 MFMA (was 16 ds_read_b64 + 64 MFMA).
// A frag: 32 contiguous bytes/lane, k = (lane>>4)*32 within K=128 blk.
// ------------------------------------------------------------------
__global__ __launch_bounds__(256, 2) void gemm_exp_kernel(
    const unsigned char* __restrict__ xn8, const unsigned char* __restrict__ yn8,
    float* __restrict__ rowpart, float* __restrict__ colpartW,
    float* __restrict__ rowsumG, float* __restrict__ colsumG, int use_scratch) {
  __shared__ unsigned char lds[4][2][8192];   // 64 KB: per-wave double buffer

  const int tid = threadIdx.x;
  const int lane = tid & 63;
  const int wid = tid >> 6;
  const int grp = lane >> 4, li = lane & 15;

  const int bid = blockIdx.x;
  const int chunk = bid & 7;               // XCD round-robin; 512KB B/XCD in L2
  const int band = (bid >> 3) * 4 + wid;   // 0..255 (64-row band per wave)
  const int rowBase = band * 64;
  const int colBase = chunk * CH;

  // ---- A: 64 rows x 256 K fp8 -> a[4][2] i32x8 (64 VGPR) ----
  // k-layout for 16x16x128: lane row = li, k = kb*128 + grp*32 + [0,32)
  i32x8 a[4][2];
  #pragma unroll
  for (int m = 0; m < 4; ++m)
    #pragma unroll
    for (int kb = 0; kb < 2; ++kb) {
      const int row = rowBase + m * 16 + li;
      a[m][kb] = *reinterpret_cast<const i32x8*>(
          xn8 + (size_t)row * DIM + kb * 128 + grp * 32);
    }

  float rsum[4][4];
  #pragma unroll
  for (int m = 0; m < 4; ++m)
    #pragma unroll
    for (int j = 0; j < 4; ++j) rsum[m][j] = 0.0f;

  unsigned char* slab0 = &lds[wid][0][0];
  unsigned char* slab1 = &lds[wid][1][0];
  const int sw = li & 7;                    // read-side XOR (matches stage)
  const int g2 = grp * 2;                   // granule base within K=128 block

  stage_wave(yn8, colBase, slab0, lane);
  __builtin_amdgcn_sched_barrier(0);

  for (int t = 0; t < NT; ++t) {
    // issue stage(t+1) first, then wait for stage(t):
    // outstanding (issue order): [stage(t) 8][stores(t-1) 2][stage(t+1) 8]
    if (t + 1 < NT)
      stage_wave(yn8, colBase + (t + 1) * 32, (t & 1) ? slab0 : slab1, lane);
    __builtin_amdgcn_sched_barrier(0);
    if (t == 0)          asm volatile("s_waitcnt vmcnt(8)" ::: "memory");
    else if (t + 1 < NT) asm volatile("s_waitcnt vmcnt(10)" ::: "memory");
    else                 asm volatile("s_waitcnt vmcnt(2)" ::: "memory");
    __builtin_amdgcn_sched_barrier(0);

    const unsigned char* Bp = (t & 1) ? slab1 : slab0;
    const unsigned char* colp0 = Bp + (size_t)li * 256;        // cols 0..15
    const unsigned char* colp1 = Bp + (size_t)(li + 16) * 256; // cols 16..31
    f32x4 acc[4][2];
    #pragma unroll
    for (int m = 0; m < 4; ++m) { acc[m][0] = (f32x4)(0.0f); acc[m][1] = (f32x4)(0.0f); }

    __builtin_amdgcn_s_setprio(1);
    #pragma unroll
    for (int kb = 0; kb < 2; ++kb) {
      // B frags: 32B/lane = global granules (kb*8+g2, +1), XOR-swizzled slots
      const int s0 = ((kb * 8 + g2) ^ sw) << 4;
      const int s1 = ((kb * 8 + g2 + 1) ^ sw) << 4;
      const i32x4 b0lo = *reinterpret_cast<const i32x4*>(colp0 + s0);
      const i32x4 b0hi = *reinterpret_cast<const i32x4*>(colp0 + s1);
      const i32x4 b1lo = *reinterpret_cast<const i32x4*>(colp1 + s0);
      const i32x4 b1hi = *reinterpret_cast<const i32x4*>(colp1 + s1);
      const i32x8 b0 = __builtin_shufflevector(b0lo, b0hi, 0, 1, 2, 3, 4, 5, 6, 7);
      const i32x8 b1 = __builtin_shufflevector(b1lo, b1hi, 0, 1, 2, 3, 4, 5, 6, 7);
      #pragma unroll
      for (int m = 0; m < 4; ++m) {
        acc[m][0] = __builtin_amdgcn_mfma_scale_f32_16x16x128_f8f6f4(
            a[m][kb], b0, acc[m][0], 0, 0, 0, 127, 0, 127);
        acc[m][1] = __builtin_amdgcn_mfma_scale_f32_16x16x128_f8f6f4(
            a[m][kb], b1, acc[m][1], 0, 0, 0, 127, 0, 127);
      }
    }
    __builtin_amdgcn_s_setprio(0);

    // ---- epilogue: exp2 + row/col partials [verbatim R12] ----
    float cs0 = 0.0f, cs1 = 0.0f;
    #pragma unroll
    for (int m = 0; m < 4; ++m) {
      #pragma unroll
      for (int j = 0; j < 4; ++j) {
        const float e0 = fexp2(acc[m][0][j]);
        const float e1 = fexp2(acc[m][1][j]);
        rsum[m][j] += e0 + e1;
        cs0 += e0;
        cs1 += e1;
      }
    }
    cs0 += __shfl_xor(cs0, 16); cs0 += __shfl_xor(cs0, 32);
    cs1 += __shfl_xor(cs1, 16); cs1 += __shfl_xor(cs1, 32);
    if (grp == 0) {  // exactly 2 vmem ops per wave per tile (vmcnt audit)
      const int c = colBase + t * 32 + li;
      if (use_scratch) {
        colpartW[(size_t)band * N_ROWS + c] = cs0;
        colpartW[(size_t)band * N_ROWS + c + 16] = cs1;
      } else {
        atomicAdd(&colsumG[c], cs0);
        atomicAdd(&colsumG[c + 16], cs1);
      }
    }
  }

  // ---- row sums: wave-exclusive rows, direct write [verbatim R12] ----
  #pragma unroll
  for (int m = 0; m < 4; ++m) {
    #pragma unroll
    for (int j = 0; j < 4; ++j) {
      float v = rsum[m][j];
      v += __shfl_xor(v, 1); v += __shfl_xor(v, 2);
      v += __shfl_xor(v, 4); v += __shfl_xor(v, 8);
      if (li == 0) {
        const int r = rowBase + m * 16 + grp * 4 + j;
        if (use_scratch) rowpart[(size_t)chunk * N_ROWS + r] = v;
        else atomicAdd(&rowsumG[r], v);
      }
    }
  }
}

// ------------------------------------------------------------------
// Kernel 3: reduce partials + final loss. [verbatim R12]
// ------------------------------------------------------------------
__global__ __launch_bounds__(256) void finalize_kernel(
    const float* __restrict__ rowpart, const float* __restrict__ colpartW,
    const float* __restrict__ rowsumG, const float* __restrict__ colsumG,
    const float* __restrict__ diagF, float* __restrict__ out, int use_scratch) {
  __shared__ float red[4];
  const int i = blockIdx.x * 256 + threadIdx.x;
  float rs, cs;
  if (use_scratch) {
    rs = 0.0f;
    #pragma unroll
    for (int c = 0; c < 8; ++c) rs += rowpart[(size_t)c * N_ROWS + i];
    cs = 0.0f;
    #pragma unroll 8
    for (int b = 0; b < 256; ++b) cs += colpartW[(size_t)b * N_ROWS + i];
  } else {
    rs = rowsumG[i];
    cs = colsumG[i];
  }
  const float d = diagF[i];
  const float e8 = fexp2(LOG2E * d);          // ~= gemm's exp2(S'_ii)
  const float mm = __expf(d - MARGINF);
  float v = mm / (mm + rs - e8) + mm / (mm + cs - e8);
  #pragma unroll
  for (int off = 32; off; off >>= 1) v += __shfl_xor(v, off);
  if ((threadIdx.x & 63) == 0) red[threadIdx.x >> 6] = v;
  __syncthreads();
  if (threadIdx.x == 0) {
    const float t = red[0] + red[1] + red[2] + red[3];
    atomicAdd(out, -t / (float)N_ROWS);
  }
}

// ------------------------------------------------------------------
extern "C" void kernel_launch(void* const* d_in, const int* in_sizes, int n_in,
                              void* d_out, int out_size, void* d_ws, size_t ws_size,
                              hipStream_t stream) {
  const float* x = (const float*)d_in[0];
  const float* y = (const float*)d_in[1];
  char* ws = (char*)d_ws;
  unsigned char* xn8 = (unsigned char*)ws;                   // 4 MiB
  unsigned char* yn8 = (unsigned char*)(ws + (4u << 20));    // 4 MiB
  float* diagF    = (float*)(ws + (8u << 20));               // 64 KiB
  float* rowpart  = (float*)(ws + (8u << 20) + 65536);       // 512 KiB [8][N]
  float* colpartW = (float*)(ws + (8u << 20) + 65536 + 524288);  // 16 MiB [256][N]
  float* rowsumG = rowpart;                                  // fallback aliases
  float* colsumG = rowpart + N_ROWS;
  const size_t need_scratch = (8u << 20) + 65536 + 524288 + (16u << 20);
  const int use_scratch = (ws_size >= need_scratch) ? 1 : 0;

  hipMemsetAsync(d_out, 0, sizeof(float), stream);
  if (!use_scratch) hipMemsetAsync(rowsumG, 0, 2 * N_ROWS * sizeof(float), stream);
  normalize_kernel<<<4096, 256, 0, stream>>>(x, y, (unsigned int*)xn8,
                                             (unsigned int*)yn8, diagF);
  gemm_exp_kernel<<<512, 256, 0, stream>>>(xn8, yn8, rowpart, colpartW,
                                           rowsumG, colsumG, use_scratch);
  finalize_kernel<<<64, 256, 0, stream>>>(rowpart, colpartW, rowsumG, colsumG,
                                          diagF, (float*)d_out, use_scratch);
}

// Round 14
// 118.882 us; speedup vs baseline: 5.8645x; 1.0667x over previous
//
#include <hip/hip_runtime.h>

#define N_ROWS 16384
#define DIM 256
#define MARGINF 0.3f
#define CH 1024
#define NT 64            // 16-col tiles per chunk
#define LOG2E 1.44269504089f

typedef float f32x4 __attribute__((ext_vector_type(4)));
typedef int i32x4 __attribute__((ext_vector_type(4)));
typedef int i32x8 __attribute__((ext_vector_type(8)));

__device__ __forceinline__ float fexp2(float x) {
#if __has_builtin(__builtin_amdgcn_exp2f)
  return __builtin_amdgcn_exp2f(x);
#else
  return exp2f(x);
#endif
}

// ------------------------------------------------------------------
// float -> OCP e4m3fn (manual fallback)
// ------------------------------------------------------------------
__device__ __forceinline__ unsigned char to_e4m3(float f) {
  unsigned u = __float_as_uint(f);
  unsigned sign = (u >> 24) & 0x80u;
  float a = fabsf(f);
  if (a >= 448.0f) return (unsigned char)(sign | 0x7eu);
  if (a < 0.015625f) {
    int q = (int)(a * 512.0f + 0.5f);
    return (unsigned char)(sign | (unsigned)q);
  }
  int e;
  float m = frexpf(a, &e);
  float mant = 2.0f * m;
  int e8 = e - 1;
  int mb = (int)(mant * 8.0f + 0.5f) - 8;
  if (mb == 8) { mb = 0; ++e8; if (e8 > 8) return (unsigned char)(sign | 0x7eu); }
  return (unsigned char)(sign | (unsigned)((e8 + 7) << 3) | (unsigned)mb);
}

__device__ __forceinline__ unsigned int pack4_e4m3(float a, float b, float c, float d) {
#if __has_builtin(__builtin_amdgcn_cvt_pk_fp8_f32)
  int lo = __builtin_amdgcn_cvt_pk_fp8_f32(a, b, 0, false);
  int r = __builtin_amdgcn_cvt_pk_fp8_f32(c, d, lo, true);
  return (unsigned int)r;
#else
  return (unsigned int)to_e4m3(a) | ((unsigned int)to_e4m3(b) << 8) |
         ((unsigned int)to_e4m3(c) << 16) | ((unsigned int)to_e4m3(d) << 24);
#endif
}

// ------------------------------------------------------------------
// Kernel 1: norms + exact fp32 diag cosine + fp8 rows.
// x-side pre-scaled by log2(e) so the GEMM's exp(S) = exp2(S').
// ------------------------------------------------------------------
__global__ __launch_bounds__(256) void normalize_kernel(
    const float* __restrict__ x, const float* __restrict__ y,
    unsigned int* __restrict__ xn8, unsigned int* __restrict__ yn8,
    float* __restrict__ diagF) {
  const int wid = threadIdx.x >> 6;
  const int lane = threadIdx.x & 63;
  const int r = blockIdx.x * 4 + wid;  // 0..16383
  const float4 vx = *reinterpret_cast<const float4*>(x + (size_t)r * DIM + lane * 4);
  const float4 vy = *reinterpret_cast<const float4*>(y + (size_t)r * DIM + lane * 4);
  float sx = vx.x * vx.x + vx.y * vx.y + vx.z * vx.z + vx.w * vx.w;
  float sy = vy.x * vy.x + vy.y * vy.y + vy.z * vy.z + vy.w * vy.w;
  float sxy = vx.x * vy.x + vx.y * vy.y + vx.z * vy.z + vx.w * vy.w;
  #pragma unroll
  for (int off = 32; off; off >>= 1) {
    sx += __shfl_xor(sx, off);
    sy += __shfl_xor(sy, off);
    sxy += __shfl_xor(sxy, off);
  }
  const float scx = LOG2E / fmaxf(sqrtf(sx), 1e-8f);   // log2e folded into A
  const float scy = 1.0f / fmaxf(sqrtf(sy), 1e-8f);
  if (lane == 0) diagF[r] = sxy * (scx / LOG2E) * scy;
  xn8[(size_t)r * 64 + lane] = pack4_e4m3(vx.x * scx, vx.y * scx, vx.z * scx, vx.w * scx);
  yn8[(size_t)r * 64 + lane] = pack4_e4m3(vy.x * scy, vy.y * scy, vy.z * scy, vy.w * scy);
}

// ------------------------------------------------------------------
// Per-WAVE stage: 16 cols x 256 K fp8 (4 KB) into this wave's slab.
// Granule XOR-swizzle (col&7) on the GLOBAL side, linear LDS dest.
// [same verified scheme as R12/R13, halved width]
// ------------------------------------------------------------------
__device__ __forceinline__ void stage_wave(const unsigned char* __restrict__ src,
                                           int colBase16, unsigned char* slab, int lane) {
  #pragma unroll
  for (int it = 0; it < 4; ++it) {
    const int id = it * 64 + lane;      // 256 x 16B granules
    const int col = id >> 4;            // 0..15
    const int slot = id & 15;
    const unsigned char* gp =
        src + (unsigned)((colBase16 + col) * DIM + ((slot ^ (col & 7)) << 4));
    unsigned char* l = slab + it * 1024;  // wave-uniform base (+lane*16 by HW)
    __builtin_amdgcn_global_load_lds(
        (const __attribute__((address_space(1))) unsigned int*)gp,
        (__attribute__((address_space(3))) unsigned int*)l, 16, 0, 0);
  }
}

// ------------------------------------------------------------------
// Kernel 2: barrier-free MX-fp8 GEMM + exp2, 4 waves/SIMD.
// R13's structure with halved per-wave tile: wave = 64-row band x
// 1024-col chunk, 16-col tiles, slab 2x4KB -> 32KB LDS/block ->
// 4 blocks/CU x 4 waves = 16 waves/CU = 4 independent waves/SIMD.
// Counted per-wave vmcnt ([stage(t)4][store 1][stage(t+1)4] ->
// 4/5/1), zero __syncthreads.
// ------------------------------------------------------------------
__global__ __launch_bounds__(256, 2) void gemm_exp_kernel(
    const unsigned char* __restrict__ xn8, const unsigned char* __restrict__ yn8,
    float* __restrict__ rowpart, float* __restrict__ colpartW,
    float* __restrict__ rowsumG, float* __restrict__ colsumG, int use_scratch) {
  __shared__ unsigned char lds[4][2][4096];   // 32 KB: per-wave double buffer

  const int tid = threadIdx.x;
  const int lane = tid & 63;
  const int wid = tid >> 6;
  const int grp = lane >> 4, li = lane & 15;

  const int bid = blockIdx.x;                // 0..1023
  const int xcd = bid & 7;
  const int rest = bid >> 3;                 // 0..127
  const int chunk = xcd * 2 + (rest >> 6);   // 0..15 (2 chunks/XCD -> L2)
  const int band = ((rest & 63) << 2) + wid; // 0..255 (64-row band per wave)
  const int rowBase = band * 64;
  const int colBase = chunk * CH;

  // ---- A: 64 rows x 256 K fp8 -> a[4][2] i32x8 (64 VGPR) ----
  // k-layout for 16x16x128: lane row = li, k = kb*128 + grp*32 + [0,32)
  i32x8 a[4][2];
  #pragma unroll
  for (int m = 0; m < 4; ++m)
    #pragma unroll
    for (int kb = 0; kb < 2; ++kb) {
      const int row = rowBase + m * 16 + li;
      a[m][kb] = *reinterpret_cast<const i32x8*>(
          xn8 + (size_t)row * DIM + kb * 128 + grp * 32);
    }

  float rsum[4][4];
  #pragma unroll
  for (int m = 0; m < 4; ++m)
    #pragma unroll
    for (int j = 0; j < 4; ++j) rsum[m][j] = 0.0f;

  unsigned char* slab0 = &lds[wid][0][0];
  unsigned char* slab1 = &lds[wid][1][0];
  const int sw = li & 7;                    // read-side XOR (matches stage)
  const int g2 = grp * 2;                   // granule base within K=128 block

  stage_wave(yn8, colBase, slab0, lane);
  __builtin_amdgcn_sched_barrier(0);

  for (int t = 0; t < NT; ++t) {
    // issue stage(t+1) first, then wait for stage(t):
    // outstanding (issue order): [stage(t) 4][store(t-1) 1][stage(t+1) 4]
    if (t + 1 < NT)
      stage_wave(yn8, colBase + (t + 1) * 16, (t & 1) ? slab0 : slab1, lane);
    __builtin_amdgcn_sched_barrier(0);
    if (t == 0)          asm volatile("s_waitcnt vmcnt(4)" ::: "memory");
    else if (t + 1 < NT) asm volatile("s_waitcnt vmcnt(5)" ::: "memory");
    else                 asm volatile("s_waitcnt vmcnt(1)" ::: "memory");
    __builtin_amdgcn_sched_barrier(0);

    const unsigned char* Bp = (t & 1) ? slab1 : slab0;
    const unsigned char* colp = Bp + (size_t)li * 256;   // this lane's col
    f32x4 acc[4];
    #pragma unroll
    for (int m = 0; m < 4; ++m) acc[m] = (f32x4)(0.0f);

    __builtin_amdgcn_s_setprio(1);
    #pragma unroll
    for (int kb = 0; kb < 2; ++kb) {
      // B frag: 32B/lane = global granules (kb*8+g2, +1), XOR-swizzled slots
      const int s0 = ((kb * 8 + g2) ^ sw) << 4;
      const int s1 = ((kb * 8 + g2 + 1) ^ sw) << 4;
      const i32x4 blo = *reinterpret_cast<const i32x4*>(colp + s0);
      const i32x4 bhi = *reinterpret_cast<const i32x4*>(colp + s1);
      const i32x8 b = __builtin_shufflevector(blo, bhi, 0, 1, 2, 3, 4, 5, 6, 7);
      #pragma unroll
      for (int m = 0; m < 4; ++m)
        acc[m] = __builtin_amdgcn_mfma_scale_f32_16x16x128_f8f6f4(
            a[m][kb], b, acc[m], 0, 0, 0, 127, 0, 127);
    }
    __builtin_amdgcn_s_setprio(0);

    // ---- epilogue: exp2 + row/col partials ----
    float cs = 0.0f;
    #pragma unroll
    for (int m = 0; m < 4; ++m) {
      #pragma unroll
      for (int j = 0; j < 4; ++j) {
        const float e = fexp2(acc[m][j]);
        rsum[m][j] += e;
        cs += e;
      }
    }
    cs += __shfl_xor(cs, 16);
    cs += __shfl_xor(cs, 32);
    if (grp == 0) {  // exactly 1 vmem op per wave per tile (vmcnt audit)
      const int c = colBase + t * 16 + li;
      if (use_scratch) colpartW[(size_t)band * N_ROWS + c] = cs;
      else atomicAdd(&colsumG[c], cs);
    }
  }

  // ---- row sums: wave-exclusive rows, direct write ----
  #pragma unroll
  for (int m = 0; m < 4; ++m) {
    #pragma unroll
    for (int j = 0; j < 4; ++j) {
      float v = rsum[m][j];
      v += __shfl_xor(v, 1); v += __shfl_xor(v, 2);
      v += __shfl_xor(v, 4); v += __shfl_xor(v, 8);
      if (li == 0) {
        const int r = rowBase + m * 16 + grp * 4 + j;
        if (use_scratch) rowpart[(size_t)chunk * N_ROWS + r] = v;
        else atomicAdd(&rowsumG[r], v);
      }
    }
  }
}

// ------------------------------------------------------------------
// Kernel 3: reduce partials + final loss. e8 uses the fp32 diagonal
// (error vs in-matrix fp8 diagonal ~1e-10 on output; budget 1.8e-6).
// ------------------------------------------------------------------
__global__ __launch_bounds__(256) void finalize_kernel(
    const float* __restrict__ rowpart, const float* __restrict__ colpartW,
    const float* __restrict__ rowsumG, const float* __restrict__ colsumG,
    const float* __restrict__ diagF, float* __restrict__ out, int use_scratch) {
  __shared__ float red[4];
  const int i = blockIdx.x * 256 + threadIdx.x;
  float rs, cs;
  if (use_scratch) {
    rs = 0.0f;
    #pragma unroll
    for (int c = 0; c < 16; ++c) rs += rowpart[(size_t)c * N_ROWS + i];
    cs = 0.0f;
    #pragma unroll 8
    for (int b = 0; b < 256; ++b) cs += colpartW[(size_t)b * N_ROWS + i];
  } else {
    rs = rowsumG[i];
    cs = colsumG[i];
  }
  const float d = diagF[i];
  const float e8 = fexp2(LOG2E * d);          // ~= gemm's exp2(S'_ii)
  const float mm = __expf(d - MARGINF);
  float v = mm / (mm + rs - e8) + mm / (mm + cs - e8);
  #pragma unroll
  for (int off = 32; off; off >>= 1) v += __shfl_xor(v, off);
  if ((threadIdx.x & 63) == 0) red[threadIdx.x >> 6] = v;
  __syncthreads();
  if (threadIdx.x == 0) {
    const float t = red[0] + red[1] + red[2] + red[3];
    atomicAdd(out, -t / (float)N_ROWS);
  }
}

// ------------------------------------------------------------------
extern "C" void kernel_launch(void* const* d_in, const int* in_sizes, int n_in,
                              void* d_out, int out_size, void* d_ws, size_t ws_size,
                              hipStream_t stream) {
  const float* x = (const float*)d_in[0];
  const float* y = (const float*)d_in[1];
  char* ws = (char*)d_ws;
  unsigned char* xn8 = (unsigned char*)ws;                   // 4 MiB
  unsigned char* yn8 = (unsigned char*)(ws + (4u << 20));    // 4 MiB
  float* diagF    = (float*)(ws + (8u << 20));               // 64 KiB
  float* rowpart  = (float*)(ws + (8u << 20) + 65536);       // 1 MiB [16][N]
  float* colpartW = (float*)(ws + (8u << 20) + 65536 + (1u << 20));  // 16 MiB [256][N]
  float* rowsumG = rowpart;                                  // fallback aliases
  float* colsumG = rowpart + N_ROWS;
  const size_t need_scratch = (8u << 20) + 65536 + (1u << 20) + (16u << 20);
  const int use_scratch = (ws_size >= need_scratch) ? 1 : 0;

  hipMemsetAsync(d_out, 0, sizeof(float), stream);
  if (!use_scratch) hipMemsetAsync(rowsumG, 0, 2 * N_ROWS * sizeof(float), stream);
  normalize_kernel<<<4096, 256, 0, stream>>>(x, y, (unsigned int*)xn8,
                                             (unsigned int*)yn8, diagF);
  gemm_exp_kernel<<<1024, 256, 0, stream>>>(xn8, yn8, rowpart, colpartW,
                                            rowsumG, colsumG, use_scratch);
  finalize_kernel<<<64, 256, 0, stream>>>(rowpart, colpartW, rowsumG, colsumG,
                                          diagF, (float*)d_out, use_scratch);
}

// Round 15
// 104.964 us; speedup vs baseline: 6.6421x; 1.1326x over previous
//
#include <hip/hip_runtime.h>

#define N_ROWS 16384
#define DIM 256
#define MARGINF 0.3f
#define CH 1024
#define NT 64            // 16-col tiles per chunk
#define LOG2E 1.44269504089f

typedef float f32x4 __attribute__((ext_vector_type(4)));
typedef int i32x8 __attribute__((ext_vector_type(8)));

__device__ __forceinline__ float fexp2(float x) {
#if __has_builtin(__builtin_amdgcn_exp2f)
  return __builtin_amdgcn_exp2f(x);
#else
  return exp2f(x);
#endif
}

// ------------------------------------------------------------------
// float -> OCP e4m3fn (manual fallback)
// ------------------------------------------------------------------
__device__ __forceinline__ unsigned char to_e4m3(float f) {
  unsigned u = __float_as_uint(f);
  unsigned sign = (u >> 24) & 0x80u;
  float a = fabsf(f);
  if (a >= 448.0f) return (unsigned char)(sign | 0x7eu);
  if (a < 0.015625f) {
    int q = (int)(a * 512.0f + 0.5f);
    return (unsigned char)(sign | (unsigned)q);
  }
  int e;
  float m = frexpf(a, &e);
  float mant = 2.0f * m;
  int e8 = e - 1;
  int mb = (int)(mant * 8.0f + 0.5f) - 8;
  if (mb == 8) { mb = 0; ++e8; if (e8 > 8) return (unsigned char)(sign | 0x7eu); }
  return (unsigned char)(sign | (unsigned)((e8 + 7) << 3) | (unsigned)mb);
}

__device__ __forceinline__ unsigned int pack4_e4m3(float a, float b, float c, float d) {
#if __has_builtin(__builtin_amdgcn_cvt_pk_fp8_f32)
  int lo = __builtin_amdgcn_cvt_pk_fp8_f32(a, b, 0, false);
  int r = __builtin_amdgcn_cvt_pk_fp8_f32(c, d, lo, true);
  return (unsigned int)r;
#else
  return (unsigned int)to_e4m3(a) | ((unsigned int)to_e4m3(b) << 8) |
         ((unsigned int)to_e4m3(c) << 16) | ((unsigned int)to_e4m3(d) << 24);
#endif
}

// ------------------------------------------------------------------
// Kernel 1: norms + exact fp32 diag cosine + fp8 outputs.
// x: row-major xn8 (A-side, log2e-folded). y: FRAGMENT-MAJOR ybf:
// ybf[(tile*2+kb)*2048 + (grp*16 + col%16)*32 + (k%32)] — exactly the
// MFMA B-operand lane order (lane = grp*16+li), so the GEMM's B load
// is base + lane*32, perfectly coalesced.
// ------------------------------------------------------------------
__global__ __launch_bounds__(256) void normalize_kernel(
    const float* __restrict__ x, const float* __restrict__ y,
    unsigned int* __restrict__ xn8, unsigned char* __restrict__ ybf,
    float* __restrict__ diagF) {
  const int wid = threadIdx.x >> 6;
  const int lane = threadIdx.x & 63;
  const int r = blockIdx.x * 4 + wid;  // 0..16383
  const float4 vx = *reinterpret_cast<const float4*>(x + (size_t)r * DIM + lane * 4);
  const float4 vy = *reinterpret_cast<const float4*>(y + (size_t)r * DIM + lane * 4);
  float sx = vx.x * vx.x + vx.y * vx.y + vx.z * vx.z + vx.w * vx.w;
  float sy = vy.x * vy.x + vy.y * vy.y + vy.z * vy.z + vy.w * vy.w;
  float sxy = vx.x * vy.x + vx.y * vy.y + vx.z * vy.z + vx.w * vy.w;
  #pragma unroll
  for (int off = 32; off; off >>= 1) {
    sx += __shfl_xor(sx, off);
    sy += __shfl_xor(sy, off);
    sxy += __shfl_xor(sxy, off);
  }
  const float scx = LOG2E / fmaxf(sqrtf(sx), 1e-8f);   // log2e folded into A
  const float scy = 1.0f / fmaxf(sqrtf(sy), 1e-8f);
  if (lane == 0) diagF[r] = sxy * (scx / LOG2E) * scy;
  xn8[(size_t)r * 64 + lane] = pack4_e4m3(vx.x * scx, vx.y * scx, vx.z * scx, vx.w * scx);
  // y fragment-major: this lane's 4 bytes cover k = [4*lane, 4*lane+4)
  const unsigned int py = pack4_e4m3(vy.x * scy, vy.y * scy, vy.z * scy, vy.w * scy);
  const int t2 = (r >> 4) * 2 + (lane >> 5);             // tile*2 + kb
  const int fl = ((lane >> 3) & 3) * 16 + (r & 15);      // fragment lane
  const unsigned dst = (unsigned)t2 * 2048 + (unsigned)fl * 32 + (lane & 7) * 4;
  *reinterpret_cast<unsigned int*>(ybf + dst) = py;
}

// ------------------------------------------------------------------
// Kernel 2: barrier-free, LDS-free MX-fp8 GEMM + exp2.
// Wave = 64-row band x 1024-col chunk. A in regs (a[4][2], 64 VGPR).
// B: direct global->reg from fragment-major ybf — 2 x 32B/lane
// coalesced loads per tile, no LDS, no staging, no waits. acc chain
// starts from a persistent zero vector (no per-tile acc init).
// 4 waves/SIMD (no LDS; VGPR capped 128 via launch_bounds(256,4)).
// ------------------------------------------------------------------
__global__ __launch_bounds__(256, 4) void gemm_exp_kernel(
    const unsigned char* __restrict__ xn8, const unsigned char* __restrict__ ybf,
    float* __restrict__ rowpart, float* __restrict__ colpartW,
    float* __restrict__ rowsumG, float* __restrict__ colsumG, int use_scratch) {
  const int tid = threadIdx.x;
  const int lane = tid & 63;
  const int wid = tid >> 6;
  const int grp = lane >> 4, li = lane & 15;

  const int bid = blockIdx.x;                // 0..1023
  const int xcd = bid & 7;
  const int rest = bid >> 3;                 // 0..127
  const int chunk = xcd * 2 + (rest >> 6);   // 0..15 (2 chunks/XCD -> L2)
  const int band = ((rest & 63) << 2) + wid; // 0..255 (64-row band per wave)
  const int rowBase = band * 64;
  const int colBase = chunk * CH;

  // ---- A: 64 rows x 256 K fp8 -> a[4][2] i32x8 (64 VGPR) ----
  i32x8 a[4][2];
  #pragma unroll
  for (int m = 0; m < 4; ++m)
    #pragma unroll
    for (int kb = 0; kb < 2; ++kb) {
      const int row = rowBase + m * 16 + li;
      a[m][kb] = *reinterpret_cast<const i32x8*>(
          xn8 + (size_t)row * DIM + kb * 128 + grp * 32);
    }

  float rsum[4][4];
  #pragma unroll
  for (int m = 0; m < 4; ++m)
    #pragma unroll
    for (int j = 0; j < 4; ++j) rsum[m][j] = 0.0f;

  const f32x4 z4 = (f32x4)(0.0f);
  // per-lane B pointer: chunk base + lane's 32B fragment slot
  const unsigned char* yb = ybf + (size_t)chunk * (NT * 4096) + (size_t)lane * 32;

  for (int t = 0; t < NT; ++t) {
    const i32x8 b0 = *reinterpret_cast<const i32x8*>(yb);         // kb=0
    const i32x8 b1 = *reinterpret_cast<const i32x8*>(yb + 2048);  // kb=1
    yb += 4096;

    f32x4 acc[4];
    __builtin_amdgcn_s_setprio(1);
    #pragma unroll
    for (int m = 0; m < 4; ++m)
      acc[m] = __builtin_amdgcn_mfma_scale_f32_16x16x128_f8f6f4(
          a[m][0], b0, z4, 0, 0, 0, 127, 0, 127);
    #pragma unroll
    for (int m = 0; m < 4; ++m)
      acc[m] = __builtin_amdgcn_mfma_scale_f32_16x16x128_f8f6f4(
          a[m][1], b1, acc[m], 0, 0, 0, 127, 0, 127);
    __builtin_amdgcn_s_setprio(0);

    // ---- epilogue: exp2 + row/col partials ----
    float cs = 0.0f;
    #pragma unroll
    for (int m = 0; m < 4; ++m) {
      #pragma unroll
      for (int j = 0; j < 4; ++j) {
        const float e = fexp2(acc[m][j]);
        rsum[m][j] += e;
        cs += e;
      }
    }
    cs += __shfl_xor(cs, 16);
    cs += __shfl_xor(cs, 32);
    if (grp == 0) {
      const int c = colBase + t * 16 + li;
      if (use_scratch) colpartW[(size_t)band * N_ROWS + c] = cs;
      else atomicAdd(&colsumG[c], cs);
    }
  }

  // ---- row sums: wave-exclusive rows, direct write ----
  #pragma unroll
  for (int m = 0; m < 4; ++m) {
    #pragma unroll
    for (int j = 0; j < 4; ++j) {
      float v = rsum[m][j];
      v += __shfl_xor(v, 1); v += __shfl_xor(v, 2);
      v += __shfl_xor(v, 4); v += __shfl_xor(v, 8);
      if (li == 0) {
        const int r = rowBase + m * 16 + grp * 4 + j;
        if (use_scratch) rowpart[(size_t)chunk * N_ROWS + r] = v;
        else atomicAdd(&rowsumG[r], v);
      }
    }
  }
}

// ------------------------------------------------------------------
// Kernel 3: reduce partials + final loss. [verbatim R14]
// ------------------------------------------------------------------
__global__ __launch_bounds__(256) void finalize_kernel(
    const float* __restrict__ rowpart, const float* __restrict__ colpartW,
    const float* __restrict__ rowsumG, const float* __restrict__ colsumG,
    const float* __restrict__ diagF, float* __restrict__ out, int use_scratch) {
  __shared__ float red[4];
  const int i = blockIdx.x * 256 + threadIdx.x;
  float rs, cs;
  if (use_scratch) {
    rs = 0.0f;
    #pragma unroll
    for (int c = 0; c < 16; ++c) rs += rowpart[(size_t)c * N_ROWS + i];
    cs = 0.0f;
    #pragma unroll 8
    for (int b = 0; b < 256; ++b) cs += colpartW[(size_t)b * N_ROWS + i];
  } else {
    rs = rowsumG[i];
    cs = colsumG[i];
  }
  const float d = diagF[i];
  const float e8 = fexp2(LOG2E * d);          // ~= gemm's exp2(S'_ii)
  const float mm = __expf(d - MARGINF);
  float v = mm / (mm + rs - e8) + mm / (mm + cs - e8);
  #pragma unroll
  for (int off = 32; off; off >>= 1) v += __shfl_xor(v, off);
  if ((threadIdx.x & 63) == 0) red[threadIdx.x >> 6] = v;
  __syncthreads();
  if (threadIdx.x == 0) {
    const float t = red[0] + red[1] + red[2] + red[3];
    atomicAdd(out, -t / (float)N_ROWS);
  }
}

// ------------------------------------------------------------------
extern "C" void kernel_launch(void* const* d_in, const int* in_sizes, int n_in,
                              void* d_out, int out_size, void* d_ws, size_t ws_size,
                              hipStream_t stream) {
  const float* x = (const float*)d_in[0];
  const float* y = (const float*)d_in[1];
  char* ws = (char*)d_ws;
  unsigned char* xn8 = (unsigned char*)ws;                   // 4 MiB
  unsigned char* ybf = (unsigned char*)(ws + (4u << 20));    // 4 MiB (frag-major)
  float* diagF    = (float*)(ws + (8u << 20));               // 64 KiB
  float* rowpart  = (float*)(ws + (8u << 20) + 65536);       // 1 MiB [16][N]
  float* colpartW = (float*)(ws + (8u << 20) + 65536 + (1u << 20));  // 16 MiB [256][N]
  float* rowsumG = rowpart;                                  // fallback aliases
  float* colsumG = rowpart + N_ROWS;
  const size_t need_scratch = (8u << 20) + 65536 + (1u << 20) + (16u << 20);
  const int use_scratch = (ws_size >= need_scratch) ? 1 : 0;

  hipMemsetAsync(d_out, 0, sizeof(float), stream);
  if (!use_scratch) hipMemsetAsync(rowsumG, 0, 2 * N_ROWS * sizeof(float), stream);
  normalize_kernel<<<4096, 256, 0, stream>>>(x, y, (unsigned int*)xn8, ybf, diagF);
  gemm_exp_kernel<<<1024, 256, 0, stream>>>(xn8, ybf, rowpart, colpartW,
                                            rowsumG, colsumG, use_scratch);
  finalize_kernel<<<64, 256, 0, stream>>>(rowpart, colpartW, rowsumG, colsumG,
                                          diagF, (float*)d_out, use_scratch);
}